// Round 1
// baseline (800.539 us; speedup 1.0000x reference)
//
#include <hip/hip_runtime.h>
#include <cstdint>
#include <cmath>

#define D_MODEL 1024
#define SEQ 2048
#define BATCH 4

typedef short bf16x8 __attribute__((ext_vector_type(8)));
typedef float f32x4 __attribute__((ext_vector_type(4)));

__device__ __forceinline__ short f2bf(float f) {
  union { float f; unsigned int u; } v; v.f = f;
  unsigned int r = (v.u + 0x7FFFu + ((v.u >> 16) & 1u)) >> 16;
  return (short)r;
}

__device__ __forceinline__ f32x4 mfma16(bf16x8 a, bf16x8 b, f32x4 c) {
  return __builtin_amdgcn_mfma_f32_16x16x32_bf16(a, b, c, 0, 0, 0);
}

__device__ __forceinline__ void load_lds16(const void* g, void* l) {
  __builtin_amdgcn_global_load_lds(
      (const __attribute__((address_space(1))) unsigned int*)g,
      (__attribute__((address_space(3))) unsigned int*)l, 16, 0, 0);
}

// ---------------- prep: x fp32 -> bf16 ----------------
__global__ __launch_bounds__(256) void convert_x(const float* __restrict__ x,
                                                 short* __restrict__ xb) {
  int i = blockIdx.x * 256 + threadIdx.x;
  float4 f = ((const float4*)x)[i];
  short4 h;
  h.x = f2bf(f.x); h.y = f2bf(f.y); h.z = f2bf(f.z); h.w = f2bf(f.w);
  ((short4*)xb)[i] = h;
}

// ---------------- prep: W [k][n] fp32 -> Wt [n][k] bf16 ----------------
__global__ __launch_bounds__(256) void transpose_w(const float* __restrict__ Wq,
                                                   const float* __restrict__ Wk,
                                                   const float* __restrict__ Wv,
                                                   short* __restrict__ wt) {
  const int mat = blockIdx.z;
  const float* __restrict__ W = (mat == 0) ? Wq : (mat == 1) ? Wk : Wv;
  short* __restrict__ o = wt + (size_t)mat * (D_MODEL * D_MODEL);
  __shared__ float tile[32][33];
  const int k0 = blockIdx.x * 32, n0 = blockIdx.y * 32;
  const int lx = threadIdx.x & 31, ly = threadIdx.x >> 5;
#pragma unroll
  for (int i = 0; i < 4; ++i) {
    int r = ly + i * 8;
    tile[r][lx] = W[(size_t)(k0 + r) * D_MODEL + n0 + lx];
  }
  __syncthreads();
#pragma unroll
  for (int i = 0; i < 4; ++i) {
    int r = ly + i * 8;
    o[(size_t)(n0 + r) * D_MODEL + k0 + lx] = f2bf(tile[lx][r]);
  }
}

// ---------------- QKV projection GEMM (m97-style) ----------------
// C[m][n] = sum_k xb[m][k] * Wt[n][k] + bias[n]
// q,k stored [m][n] bf16; v stored transposed vt[b][n][t] bf16
__global__ __launch_bounds__(256) void qkv_gemm(
    const short* __restrict__ xb, const short* __restrict__ wt,
    const float* __restrict__ bq, const float* __restrict__ bk,
    const float* __restrict__ bv, short* __restrict__ qo,
    short* __restrict__ ko, short* __restrict__ vo) {
  const int m0 = blockIdx.x * 128;
  const int n0 = blockIdx.y * 128;
  const int mat = blockIdx.z;
  const short* __restrict__ w = wt + (size_t)mat * (D_MODEL * D_MODEL);
  const float* __restrict__ bias = (mat == 0) ? bq : (mat == 1) ? bk : bv;

  __shared__ short a_lds[128 * 64];
  __shared__ short b_lds[128 * 64];

  const int tid = threadIdx.x;
  const int wid = tid >> 6;
  const int lane = tid & 63;
  const int quad = lane >> 4;
  const int l16 = lane & 15;
  const int mw = (wid >> 1) * 64;
  const int nw = (wid & 1) * 64;

  f32x4 acc[4][4] = {};

  const int r_local = wid * 8 + (lane >> 3);
  const int c_local = (lane & 7) * 8;

  for (int k0 = 0; k0 < D_MODEL; k0 += 64) {
    __syncthreads();
#pragma unroll
    for (int it = 0; it < 4; ++it) {
      const short* srcA = xb + (size_t)(m0 + it * 32 + r_local) * D_MODEL + k0 + c_local;
      load_lds16(srcA, (char*)a_lds + (it * 256 + wid * 64) * 16);
      const short* srcB = w + (size_t)(n0 + it * 32 + r_local) * D_MODEL + k0 + c_local;
      load_lds16(srcB, (char*)b_lds + (it * 256 + wid * 64) * 16);
    }
    __syncthreads();
#pragma unroll
    for (int kt = 0; kt < 2; ++kt) {
      bf16x8 af[4], bfr[4];
#pragma unroll
      for (int i = 0; i < 4; ++i)
        af[i] = *(const bf16x8*)(a_lds + (mw + i * 16 + l16) * 64 + kt * 32 + quad * 8);
#pragma unroll
      for (int i = 0; i < 4; ++i)
        bfr[i] = *(const bf16x8*)(b_lds + (nw + i * 16 + l16) * 64 + kt * 32 + quad * 8);
#pragma unroll
      for (int i = 0; i < 4; ++i)
#pragma unroll
        for (int j = 0; j < 4; ++j)
          acc[i][j] = mfma16(af[i], bfr[j], acc[i][j]);
    }
  }
#pragma unroll
  for (int i = 0; i < 4; ++i) {
#pragma unroll
    for (int j = 0; j < 4; ++j) {
#pragma unroll
      for (int r = 0; r < 4; ++r) {
        const int mrow = m0 + mw + i * 16 + quad * 4 + r;
        const int ncol = n0 + nw + j * 16 + l16;
        const float val = acc[i][j][r] + bias[ncol];
        const short h = f2bf(val);
        if (mat == 2) {
          const int bb = mrow >> 11;
          const int t = mrow & 2047;
          vo[((size_t)bb * D_MODEL + ncol) * SEQ + t] = h;
        } else if (mat == 0) {
          qo[(size_t)mrow * D_MODEL + ncol] = h;
        } else {
          ko[(size_t)mrow * D_MODEL + ncol] = h;
        }
      }
    }
  }
}

// ---------------- causal flash attention ----------------
// 8 waves/WG, each wave owns a 128-wide d-chunk. BM=16 q-rows, BN=32 kv-rows.
// WG handles q-tile pair (p, 127-p): constant 65 kv-tiles of work -> balanced.
__global__ __launch_bounds__(512, 4) void attn(const short* __restrict__ qb,
                                               const short* __restrict__ kb,
                                               const short* __restrict__ vtb,
                                               float* __restrict__ out) {
  const int pair = blockIdx.x;  // 0..63
  const int b = blockIdx.y;     // 0..3
  const int tid = threadIdx.x;
  const int wv = tid >> 6;   // 0..7
  const int lane = tid & 63;
  const int quad = lane >> 4;
  const int l16 = lane & 15;
  const int d0 = wv * 128;

  __shared__ float s_lds[8 * 16 * 33];
  __shared__ float sred[16 * 33];
  __shared__ short p_lds[16 * 40];
  __shared__ float m_s[16], l_s[16], a_s[16];

  for (int half = 0; half < 2; ++half) {
    const int q16 = (half == 0) ? pair : (127 - pair);
    const int row0 = q16 * 16;
    const int ntile = (row0 + 15) / 32 + 1;

    __syncthreads();  // protect l_s/m_s against previous half's readers
    if (tid < 16) { m_s[tid] = -__builtin_inff(); l_s[tid] = 0.0f; }

    bf16x8 qf[4];
#pragma unroll
    for (int kt = 0; kt < 4; ++kt)
      qf[kt] = *(const bf16x8*)(qb + ((size_t)b * SEQ + row0 + l16) * D_MODEL +
                                d0 + kt * 32 + quad * 8);

    f32x4 of[8] = {};

    for (int j = 0; j < ntile; ++j) {
      // --- partial S = Q K^T over this wave's d-chunk ---
      f32x4 sc0 = {}, sc1 = {};
      const short* kbase =
          kb + ((size_t)b * SEQ + j * 32 + l16) * D_MODEL + d0 + quad * 8;
#pragma unroll
      for (int kt = 0; kt < 4; ++kt) {
        bf16x8 k0f = *(const bf16x8*)(kbase + kt * 32);
        bf16x8 k1f = *(const bf16x8*)(kbase + (size_t)16 * D_MODEL + kt * 32);
        sc0 = mfma16(qf[kt], k0f, sc0);
        sc1 = mfma16(qf[kt], k1f, sc1);
      }
#pragma unroll
      for (int r = 0; r < 4; ++r) {
        s_lds[(wv * 16 + quad * 4 + r) * 33 + l16] = sc0[r];
        s_lds[(wv * 16 + quad * 4 + r) * 33 + 16 + l16] = sc1[r];
      }
      __syncthreads();
      // --- reduce 8 partials, scale, causal mask ---
      {
        const int row = tid >> 5;
        const int col = tid & 31;
        float v = 0.f;
#pragma unroll
        for (int p = 0; p < 8; ++p) v += s_lds[(p * 16 + row) * 33 + col];
        v *= 0.03125f;
        if (j * 32 + col > row0 + row) v = -__builtin_inff();
        sred[row * 33 + col] = v;
      }
      __syncthreads();
      // --- online softmax (one thread per row) ---
      if (tid < 16) {
        const int row = tid;
        float mo = m_s[row];
        float mx = mo;
#pragma unroll
        for (int c = 0; c < 32; ++c) mx = fmaxf(mx, sred[row * 33 + c]);
        const float al = __expf(mo - mx);
        float ls = 0.f;
#pragma unroll
        for (int c = 0; c < 32; ++c) {
          float p = __expf(sred[row * 33 + c] - mx);
          ls += p;
          p_lds[row * 40 + c] = f2bf(p);
        }
        m_s[row] = mx;
        l_s[row] = al * l_s[row] + ls;
        a_s[row] = al;
      }
      __syncthreads();
      // --- rescale O, then O += P @ V over this wave's d-chunk ---
      float al[4];
#pragma unroll
      for (int r = 0; r < 4; ++r) al[r] = a_s[quad * 4 + r];
      const bf16x8 pa = *(const bf16x8*)(p_lds + l16 * 40 + quad * 8);
      const short* vbase =
          vtb + ((size_t)b * D_MODEL + d0 + l16) * SEQ + j * 32 + quad * 8;
#pragma unroll
      for (int nt = 0; nt < 8; ++nt) {
        const bf16x8 vf = *(const bf16x8*)(vbase + (size_t)nt * 16 * SEQ);
#pragma unroll
        for (int r = 0; r < 4; ++r) of[nt][r] *= al[r];
        of[nt] = mfma16(pa, vf, of[nt]);
      }
    }
    // --- epilogue: divide by l, store fp32 ---
    float linv[4];
#pragma unroll
    for (int r = 0; r < 4; ++r) linv[r] = 1.0f / l_s[quad * 4 + r];
#pragma unroll
    for (int nt = 0; nt < 8; ++nt) {
#pragma unroll
      for (int r = 0; r < 4; ++r) {
        const int t = row0 + quad * 4 + r;
        const int d = d0 + nt * 16 + l16;
        out[((size_t)b * SEQ + t) * D_MODEL + d] = of[nt][r] * linv[r];
      }
    }
  }
}

extern "C" void kernel_launch(void* const* d_in, const int* in_sizes, int n_in,
                              void* d_out, int out_size, void* d_ws, size_t ws_size,
                              hipStream_t stream) {
  (void)in_sizes; (void)n_in; (void)out_size; (void)ws_size;
  const float* x  = (const float*)d_in[0];
  const float* Wq = (const float*)d_in[1];
  const float* bq = (const float*)d_in[2];
  const float* Wk = (const float*)d_in[3];
  const float* bk = (const float*)d_in[4];
  const float* Wv = (const float*)d_in[5];
  const float* bv = (const float*)d_in[6];
  float* out = (float*)d_out;

  char* ws = (char*)d_ws;
  short* xb = (short*)(ws);                 // 8192*1024 bf16 = 16 MB
  short* wt = (short*)(ws + 16777216);      // 3*1024*1024 bf16 = 6 MB
  short* qo = (short*)(ws + 23068672);      // 16 MB
  short* ko = (short*)(ws + 39845888);      // 16 MB
  short* vo = (short*)(ws + 56623104);      // 16 MB (transposed [b][d][s])

  convert_x<<<dim3(8192), dim3(256), 0, stream>>>(x, xb);
  transpose_w<<<dim3(32, 32, 3), dim3(256), 0, stream>>>(Wq, Wk, Wv, wt);
  qkv_gemm<<<dim3(64, 8, 3), dim3(256), 0, stream>>>(xb, wt, bq, bk, bv, qo, ko, vo);
  attn<<<dim3(64, BATCH), dim3(512), 0, stream>>>(qo, ko, vo, out);
}

// Round 2
// 304.938 us; speedup vs baseline: 2.6253x; 2.6253x over previous
//
#include <hip/hip_runtime.h>
#include <cstdint>
#include <cmath>

#define D_MODEL 1024
#define SEQ 2048
#define BATCH 4

typedef short bf16x8 __attribute__((ext_vector_type(8)));
typedef float f32x4 __attribute__((ext_vector_type(4)));

__device__ __forceinline__ short f2bf(float f) {
  union { float f; unsigned int u; } v; v.f = f;
  unsigned int r = (v.u + 0x7FFFu + ((v.u >> 16) & 1u)) >> 16;
  return (short)r;
}

__device__ __forceinline__ float bf2f(short h) {
  union { unsigned int u; float f; } v;
  v.u = ((unsigned int)(unsigned short)h) << 16;
  return v.f;
}

__device__ __forceinline__ f32x4 mfma16(bf16x8 a, bf16x8 b, f32x4 c) {
  return __builtin_amdgcn_mfma_f32_16x16x32_bf16(a, b, c, 0, 0, 0);
}

__device__ __forceinline__ void load_lds16(const void* g, void* l) {
  __builtin_amdgcn_global_load_lds(
      (const __attribute__((address_space(1))) unsigned int*)g,
      (__attribute__((address_space(3))) unsigned int*)l, 16, 0, 0);
}

// ---------------- prep: x fp32 -> bf16 ----------------
__global__ __launch_bounds__(256) void convert_x(const float* __restrict__ x,
                                                 short* __restrict__ xb) {
  int i = blockIdx.x * 256 + threadIdx.x;
  float4 f = ((const float4*)x)[i];
  short4 h;
  h.x = f2bf(f.x); h.y = f2bf(f.y); h.z = f2bf(f.z); h.w = f2bf(f.w);
  ((short4*)xb)[i] = h;
}

// ---------------- prep: W [k][n] fp32 -> Wt [n][k] bf16 ----------------
__global__ __launch_bounds__(256) void transpose_w(const float* __restrict__ Wq,
                                                   const float* __restrict__ Wk,
                                                   const float* __restrict__ Wv,
                                                   short* __restrict__ wt) {
  const int mat = blockIdx.z;
  const float* __restrict__ W = (mat == 0) ? Wq : (mat == 1) ? Wk : Wv;
  short* __restrict__ o = wt + (size_t)mat * (D_MODEL * D_MODEL);
  __shared__ float tile[32][33];
  const int k0 = blockIdx.x * 32, n0 = blockIdx.y * 32;
  const int lx = threadIdx.x & 31, ly = threadIdx.x >> 5;
#pragma unroll
  for (int i = 0; i < 4; ++i) {
    int r = ly + i * 8;
    tile[r][lx] = W[(size_t)(k0 + r) * D_MODEL + n0 + lx];
  }
  __syncthreads();
#pragma unroll
  for (int i = 0; i < 4; ++i) {
    int r = ly + i * 8;
    o[(size_t)(n0 + r) * D_MODEL + k0 + lx] = f2bf(tile[lx][r]);
  }
}

// ---------------- QKV projection GEMM (m97-style) ----------------
__global__ __launch_bounds__(256) void qkv_gemm(
    const short* __restrict__ xb, const short* __restrict__ wt,
    const float* __restrict__ bq, const float* __restrict__ bk,
    const float* __restrict__ bv, short* __restrict__ qo,
    short* __restrict__ ko, short* __restrict__ vo) {
  const int m0 = blockIdx.x * 128;
  const int n0 = blockIdx.y * 128;
  const int mat = blockIdx.z;
  const short* __restrict__ w = wt + (size_t)mat * (D_MODEL * D_MODEL);
  const float* __restrict__ bias = (mat == 0) ? bq : (mat == 1) ? bk : bv;

  __shared__ short a_lds[128 * 64];
  __shared__ short b_lds[128 * 64];

  const int tid = threadIdx.x;
  const int wid = tid >> 6;
  const int lane = tid & 63;
  const int quad = lane >> 4;
  const int l16 = lane & 15;
  const int mw = (wid >> 1) * 64;
  const int nw = (wid & 1) * 64;

  f32x4 acc[4][4] = {};

  const int r_local = wid * 8 + (lane >> 3);
  const int c_local = (lane & 7) * 8;

  for (int k0 = 0; k0 < D_MODEL; k0 += 64) {
    __syncthreads();
#pragma unroll
    for (int it = 0; it < 4; ++it) {
      const short* srcA = xb + (size_t)(m0 + it * 32 + r_local) * D_MODEL + k0 + c_local;
      load_lds16(srcA, (char*)a_lds + (it * 256 + wid * 64) * 16);
      const short* srcB = w + (size_t)(n0 + it * 32 + r_local) * D_MODEL + k0 + c_local;
      load_lds16(srcB, (char*)b_lds + (it * 256 + wid * 64) * 16);
    }
    __syncthreads();
#pragma unroll
    for (int kt = 0; kt < 2; ++kt) {
      bf16x8 af[4], bfr[4];
#pragma unroll
      for (int i = 0; i < 4; ++i)
        af[i] = *(const bf16x8*)(a_lds + (mw + i * 16 + l16) * 64 + kt * 32 + quad * 8);
#pragma unroll
      for (int i = 0; i < 4; ++i)
        bfr[i] = *(const bf16x8*)(b_lds + (nw + i * 16 + l16) * 64 + kt * 32 + quad * 8);
#pragma unroll
      for (int i = 0; i < 4; ++i)
#pragma unroll
        for (int j = 0; j < 4; ++j)
          acc[i][j] = mfma16(af[i], bfr[j], acc[i][j]);
    }
  }
#pragma unroll
  for (int i = 0; i < 4; ++i) {
#pragma unroll
    for (int j = 0; j < 4; ++j) {
#pragma unroll
      for (int r = 0; r < 4; ++r) {
        const int mrow = m0 + mw + i * 16 + quad * 4 + r;
        const int ncol = n0 + nw + j * 16 + l16;
        const float val = acc[i][j][r] + bias[ncol];
        const short h = f2bf(val);
        if (mat == 2) {
          const int bb = mrow >> 11;
          const int t = mrow & 2047;
          vo[((size_t)bb * D_MODEL + ncol) * SEQ + t] = h;
        } else if (mat == 0) {
          qo[(size_t)mrow * D_MODEL + ncol] = h;
        } else {
          ko[(size_t)mrow * D_MODEL + ncol] = h;
        }
      }
    }
  }
}

// ---------------- S = scale * Q K^T, causal lower-triangle tiles ----------------
// grid (16,16,4): bx=row tile, by=col tile (skip by>bx), bz=batch. S bf16 [b][t][s].
__global__ __launch_bounds__(256) void sgemm(const short* __restrict__ qb,
                                             const short* __restrict__ kb,
                                             short* __restrict__ S) {
  if (blockIdx.y > blockIdx.x) return;
  const int m0 = blockIdx.x * 128;
  const int n0 = blockIdx.y * 128;
  const int b = blockIdx.z;
  const short* __restrict__ qp = qb + (size_t)b * SEQ * D_MODEL;
  const short* __restrict__ kp = kb + (size_t)b * SEQ * D_MODEL;

  __shared__ short a_lds[128 * 64];
  __shared__ short b_lds[128 * 64];

  const int tid = threadIdx.x;
  const int wid = tid >> 6;
  const int lane = tid & 63;
  const int quad = lane >> 4;
  const int l16 = lane & 15;
  const int mw = (wid >> 1) * 64;
  const int nw = (wid & 1) * 64;

  f32x4 acc[4][4] = {};

  const int r_local = wid * 8 + (lane >> 3);
  const int c_local = (lane & 7) * 8;

  for (int k0 = 0; k0 < D_MODEL; k0 += 64) {
    __syncthreads();
#pragma unroll
    for (int it = 0; it < 4; ++it) {
      const short* srcA = qp + (size_t)(m0 + it * 32 + r_local) * D_MODEL + k0 + c_local;
      load_lds16(srcA, (char*)a_lds + (it * 256 + wid * 64) * 16);
      const short* srcB = kp + (size_t)(n0 + it * 32 + r_local) * D_MODEL + k0 + c_local;
      load_lds16(srcB, (char*)b_lds + (it * 256 + wid * 64) * 16);
    }
    __syncthreads();
#pragma unroll
    for (int kt = 0; kt < 2; ++kt) {
      bf16x8 af[4], bfr[4];
#pragma unroll
      for (int i = 0; i < 4; ++i)
        af[i] = *(const bf16x8*)(a_lds + (mw + i * 16 + l16) * 64 + kt * 32 + quad * 8);
#pragma unroll
      for (int i = 0; i < 4; ++i)
        bfr[i] = *(const bf16x8*)(b_lds + (nw + i * 16 + l16) * 64 + kt * 32 + quad * 8);
#pragma unroll
      for (int i = 0; i < 4; ++i)
#pragma unroll
        for (int j = 0; j < 4; ++j)
          acc[i][j] = mfma16(af[i], bfr[j], acc[i][j]);
    }
  }
#pragma unroll
  for (int i = 0; i < 4; ++i) {
#pragma unroll
    for (int j = 0; j < 4; ++j) {
#pragma unroll
      for (int r = 0; r < 4; ++r) {
        const int mrow = m0 + mw + i * 16 + quad * 4 + r;
        const int ncol = n0 + nw + j * 16 + l16;
        S[((size_t)b * SEQ + mrow) * SEQ + ncol] = f2bf(acc[i][j][r] * 0.03125f);
      }
    }
  }
}

// ---------------- row softmax: S bf16 -> P bf16 (normalized, zero-padded) --------
__global__ __launch_bounds__(256) void softmax_rows(const short* __restrict__ S,
                                                    short* __restrict__ P) {
  const int row = blockIdx.x;          // 0..8191
  const int t = row & (SEQ - 1);
  const int tid = threadIdx.x;
  const short* __restrict__ srow = S + (size_t)row * SEQ;
  short* __restrict__ prow = P + (size_t)row * SEQ;

  __shared__ float red[4];

  float v[8];
#pragma unroll
  for (int i = 0; i < 8; ++i) {
    const int c = tid + i * 256;
    v[i] = (c <= t) ? bf2f(srow[c]) : -1e30f;
  }
  float m = v[0];
#pragma unroll
  for (int i = 1; i < 8; ++i) m = fmaxf(m, v[i]);
#pragma unroll
  for (int o = 32; o; o >>= 1) m = fmaxf(m, __shfl_xor(m, o));
  if ((tid & 63) == 0) red[tid >> 6] = m;
  __syncthreads();
  m = fmaxf(fmaxf(red[0], red[1]), fmaxf(red[2], red[3]));

  float e[8];
  float s = 0.f;
#pragma unroll
  for (int i = 0; i < 8; ++i) {
    e[i] = __expf(v[i] - m);   // -1e30 - m underflows to 0
    s += e[i];
  }
#pragma unroll
  for (int o = 32; o; o >>= 1) s += __shfl_xor(s, o);
  __syncthreads();
  if ((tid & 63) == 0) red[tid >> 6] = s;
  __syncthreads();
  s = red[0] + red[1] + red[2] + red[3];
  const float rinv = 1.0f / s;
#pragma unroll
  for (int i = 0; i < 8; ++i) prow[tid + i * 256] = f2bf(e[i] * rinv);
}

// ---------------- O = P V  (B = V^T layout), causal-truncated K loop -------------
// grid (16,8,4): bx=row tile over t, by=d tile, bz=batch. out f32 [b][t][d].
__global__ __launch_bounds__(256) void pvgemm(const short* __restrict__ P,
                                              const short* __restrict__ vtb,
                                              float* __restrict__ out) {
  const int m0 = blockIdx.x * 128;
  const int n0 = blockIdx.y * 128;
  const int b = blockIdx.z;
  const short* __restrict__ pp = P + (size_t)b * SEQ * SEQ;
  const short* __restrict__ vp = vtb + (size_t)b * D_MODEL * SEQ;
  const int kmax = m0 + 128;

  __shared__ short a_lds[128 * 64];
  __shared__ short b_lds[128 * 64];

  const int tid = threadIdx.x;
  const int wid = tid >> 6;
  const int lane = tid & 63;
  const int quad = lane >> 4;
  const int l16 = lane & 15;
  const int mw = (wid >> 1) * 64;
  const int nw = (wid & 1) * 64;

  f32x4 acc[4][4] = {};

  const int r_local = wid * 8 + (lane >> 3);
  const int c_local = (lane & 7) * 8;

  for (int k0 = 0; k0 < kmax; k0 += 64) {
    __syncthreads();
#pragma unroll
    for (int it = 0; it < 4; ++it) {
      const short* srcA = pp + (size_t)(m0 + it * 32 + r_local) * SEQ + k0 + c_local;
      load_lds16(srcA, (char*)a_lds + (it * 256 + wid * 64) * 16);
      const short* srcB = vp + (size_t)(n0 + it * 32 + r_local) * SEQ + k0 + c_local;
      load_lds16(srcB, (char*)b_lds + (it * 256 + wid * 64) * 16);
    }
    __syncthreads();
#pragma unroll
    for (int kt = 0; kt < 2; ++kt) {
      bf16x8 af[4], bfr[4];
#pragma unroll
      for (int i = 0; i < 4; ++i)
        af[i] = *(const bf16x8*)(a_lds + (mw + i * 16 + l16) * 64 + kt * 32 + quad * 8);
#pragma unroll
      for (int i = 0; i < 4; ++i)
        bfr[i] = *(const bf16x8*)(b_lds + (nw + i * 16 + l16) * 64 + kt * 32 + quad * 8);
#pragma unroll
      for (int i = 0; i < 4; ++i)
#pragma unroll
        for (int j = 0; j < 4; ++j)
          acc[i][j] = mfma16(af[i], bfr[j], acc[i][j]);
    }
  }
#pragma unroll
  for (int i = 0; i < 4; ++i) {
#pragma unroll
    for (int j = 0; j < 4; ++j) {
#pragma unroll
      for (int r = 0; r < 4; ++r) {
        const int mrow = m0 + mw + i * 16 + quad * 4 + r;
        const int ncol = n0 + nw + j * 16 + l16;
        out[((size_t)b * SEQ + mrow) * D_MODEL + ncol] = acc[i][j][r];
      }
    }
  }
}

extern "C" void kernel_launch(void* const* d_in, const int* in_sizes, int n_in,
                              void* d_out, int out_size, void* d_ws, size_t ws_size,
                              hipStream_t stream) {
  (void)in_sizes; (void)n_in; (void)out_size; (void)ws_size;
  const float* x  = (const float*)d_in[0];
  const float* Wq = (const float*)d_in[1];
  const float* bq = (const float*)d_in[2];
  const float* Wk = (const float*)d_in[3];
  const float* bk = (const float*)d_in[4];
  const float* Wv = (const float*)d_in[5];
  const float* bv = (const float*)d_in[6];
  float* out = (float*)d_out;

  char* ws = (char*)d_ws;
  short* xb = (short*)(ws);                 // 16 MB   [dead after qkv_gemm]
  short* wt = (short*)(ws + 16777216);      // 6 MB    [dead after qkv_gemm]
  short* qo = (short*)(ws + 23068672);      // 16 MB   [dead after sgemm]
  short* ko = (short*)(ws + 39845888);      // 16 MB   [dead after sgemm]
  short* vo = (short*)(ws + 56623104);      // 16 MB   transposed [b][d][s]
  short* S  = (short*)(ws + 73400320);      // 32 MB bf16 [b][t][s]
  short* P  = (short*)(ws);                 // 32 MB, aliases xb/wt/qo (dead by then)

  convert_x<<<dim3(8192), dim3(256), 0, stream>>>(x, xb);
  transpose_w<<<dim3(32, 32, 3), dim3(256), 0, stream>>>(Wq, Wk, Wv, wt);
  qkv_gemm<<<dim3(64, 8, 3), dim3(256), 0, stream>>>(xb, wt, bq, bk, bv, qo, ko, vo);
  sgemm<<<dim3(16, 16, BATCH), dim3(256), 0, stream>>>(qo, ko, S);
  softmax_rows<<<dim3(BATCH * SEQ), dim3(256), 0, stream>>>(S, P);
  pvgemm<<<dim3(16, 8, BATCH), dim3(256), 0, stream>>>(P, vo, out);
}

// Round 3
// 289.251 us; speedup vs baseline: 2.7676x; 1.0542x over previous
//
#include <hip/hip_runtime.h>
#include <cstdint>
#include <cmath>

#define D_MODEL 1024
#define SEQ 2048
#define BATCH 4

typedef short bf16x8 __attribute__((ext_vector_type(8)));
typedef float f32x4 __attribute__((ext_vector_type(4)));

__device__ __forceinline__ short f2bf(float f) {
  union { float f; unsigned int u; } v; v.f = f;
  unsigned int r = (v.u + 0x7FFFu + ((v.u >> 16) & 1u)) >> 16;
  return (short)r;
}

__device__ __forceinline__ float bf2f(short h) {
  union { unsigned int u; float f; } v;
  v.u = ((unsigned int)(unsigned short)h) << 16;
  return v.f;
}

__device__ __forceinline__ f32x4 mfma16(bf16x8 a, bf16x8 b, f32x4 c) {
  return __builtin_amdgcn_mfma_f32_16x16x32_bf16(a, b, c, 0, 0, 0);
}

__device__ __forceinline__ void load_lds16(const void* g, void* l) {
  __builtin_amdgcn_global_load_lds(
      (const __attribute__((address_space(1))) unsigned int*)g,
      (__attribute__((address_space(3))) unsigned int*)l, 16, 0, 0);
}

// ---------------- prep: x fp32 -> bf16 ----------------
__global__ __launch_bounds__(256) void convert_x(const float* __restrict__ x,
                                                 short* __restrict__ xb) {
  int i = blockIdx.x * 256 + threadIdx.x;
  float4 f = ((const float4*)x)[i];
  short4 h;
  h.x = f2bf(f.x); h.y = f2bf(f.y); h.z = f2bf(f.z); h.w = f2bf(f.w);
  ((short4*)xb)[i] = h;
}

// ---------------- prep: W [k][n] fp32 -> Wt [n][k] bf16 ----------------
__global__ __launch_bounds__(256) void transpose_w(const float* __restrict__ Wq,
                                                   const float* __restrict__ Wk,
                                                   const float* __restrict__ Wv,
                                                   short* __restrict__ wt) {
  const int mat = blockIdx.z;
  const float* __restrict__ W = (mat == 0) ? Wq : (mat == 1) ? Wk : Wv;
  short* __restrict__ o = wt + (size_t)mat * (D_MODEL * D_MODEL);
  __shared__ float tile[32][33];
  const int k0 = blockIdx.x * 32, n0 = blockIdx.y * 32;
  const int lx = threadIdx.x & 31, ly = threadIdx.x >> 5;
#pragma unroll
  for (int i = 0; i < 4; ++i) {
    int r = ly + i * 8;
    tile[r][lx] = W[(size_t)(k0 + r) * D_MODEL + n0 + lx];
  }
  __syncthreads();
#pragma unroll
  for (int i = 0; i < 4; ++i) {
    int r = ly + i * 8;
    o[(size_t)(n0 + r) * D_MODEL + k0 + lx] = f2bf(tile[lx][r]);
  }
}

// ---------------- QKV projection GEMM: 256x128 tile, 512 threads ----------------
// C[m][n] = sum_k xb[m][k] * Wt[n][k] + bias[n]
__global__ __launch_bounds__(512) void qkv_gemm(
    const short* __restrict__ xb, const short* __restrict__ wt,
    const float* __restrict__ bq, const float* __restrict__ bk,
    const float* __restrict__ bv, short* __restrict__ qo,
    short* __restrict__ ko, short* __restrict__ vo) {
  const int m0 = blockIdx.x * 256;
  const int n0 = blockIdx.y * 128;
  const int mat = blockIdx.z;
  const short* __restrict__ w = wt + (size_t)mat * (D_MODEL * D_MODEL);
  const float* __restrict__ bias = (mat == 0) ? bq : (mat == 1) ? bk : bv;

  __shared__ short a_lds[256 * 64];  // 32 KB
  __shared__ short b_lds[128 * 64];  // 16 KB

  const int tid = threadIdx.x;
  const int wid = tid >> 6;        // 0..7
  const int lane = tid & 63;
  const int quad = lane >> 4;
  const int l16 = lane & 15;
  const int wm = (wid >> 1) * 64;  // 0,64,128,192
  const int wn = (wid & 1) * 64;   // 0,64

  f32x4 acc[4][4] = {};

  const int r_local = wid * 8 + (lane >> 3);  // 0..63
  const int c_local = (lane & 7) * 8;

  for (int k0 = 0; k0 < D_MODEL; k0 += 64) {
    __syncthreads();
#pragma unroll
    for (int it = 0; it < 4; ++it) {
      const short* srcA = xb + (size_t)(m0 + it * 64 + r_local) * D_MODEL + k0 + c_local;
      load_lds16(srcA, (char*)a_lds + it * 8192 + wid * 1024);
    }
#pragma unroll
    for (int it = 0; it < 2; ++it) {
      const short* srcB = w + (size_t)(n0 + it * 64 + r_local) * D_MODEL + k0 + c_local;
      load_lds16(srcB, (char*)b_lds + it * 8192 + wid * 1024);
    }
    __syncthreads();
#pragma unroll
    for (int kt = 0; kt < 2; ++kt) {
      bf16x8 af[4], bfr[4];
#pragma unroll
      for (int i = 0; i < 4; ++i)
        af[i] = *(const bf16x8*)(a_lds + (wm + i * 16 + l16) * 64 + kt * 32 + quad * 8);
#pragma unroll
      for (int i = 0; i < 4; ++i)
        bfr[i] = *(const bf16x8*)(b_lds + (wn + i * 16 + l16) * 64 + kt * 32 + quad * 8);
#pragma unroll
      for (int i = 0; i < 4; ++i)
#pragma unroll
        for (int j = 0; j < 4; ++j)
          acc[i][j] = mfma16(af[i], bfr[j], acc[i][j]);
    }
  }
#pragma unroll
  for (int i = 0; i < 4; ++i) {
#pragma unroll
    for (int j = 0; j < 4; ++j) {
#pragma unroll
      for (int r = 0; r < 4; ++r) {
        const int mrow = m0 + wm + i * 16 + quad * 4 + r;
        const int ncol = n0 + wn + j * 16 + l16;
        const float val = acc[i][j][r] + bias[ncol];
        const short h = f2bf(val);
        if (mat == 2) {
          const int bb = mrow >> 11;
          const int t = mrow & 2047;
          vo[((size_t)bb * D_MODEL + ncol) * SEQ + t] = h;
        } else if (mat == 0) {
          qo[(size_t)mrow * D_MODEL + ncol] = h;
        } else {
          ko[(size_t)mrow * D_MODEL + ncol] = h;
        }
      }
    }
  }
}

// ---------------- S = scale * Q K^T, causal lower-triangle tiles ----------------
// grid (16,16,4): bx=row tile, by=col tile (skip by>bx), bz=batch. S bf16 [b][t][s].
__global__ __launch_bounds__(256) void sgemm(const short* __restrict__ qb,
                                             const short* __restrict__ kb,
                                             short* __restrict__ S) {
  if (blockIdx.y > blockIdx.x) return;
  const int m0 = blockIdx.x * 128;
  const int n0 = blockIdx.y * 128;
  const int b = blockIdx.z;
  const short* __restrict__ qp = qb + (size_t)b * SEQ * D_MODEL;
  const short* __restrict__ kp = kb + (size_t)b * SEQ * D_MODEL;

  __shared__ short a_lds[128 * 64];
  __shared__ short b_lds[128 * 64];

  const int tid = threadIdx.x;
  const int wid = tid >> 6;
  const int lane = tid & 63;
  const int quad = lane >> 4;
  const int l16 = lane & 15;
  const int mw = (wid >> 1) * 64;
  const int nw = (wid & 1) * 64;

  f32x4 acc[4][4] = {};

  const int r_local = wid * 8 + (lane >> 3);
  const int c_local = (lane & 7) * 8;

  for (int k0 = 0; k0 < D_MODEL; k0 += 64) {
    __syncthreads();
#pragma unroll
    for (int it = 0; it < 4; ++it) {
      const short* srcA = qp + (size_t)(m0 + it * 32 + r_local) * D_MODEL + k0 + c_local;
      load_lds16(srcA, (char*)a_lds + (it * 256 + wid * 64) * 16);
      const short* srcB = kp + (size_t)(n0 + it * 32 + r_local) * D_MODEL + k0 + c_local;
      load_lds16(srcB, (char*)b_lds + (it * 256 + wid * 64) * 16);
    }
    __syncthreads();
#pragma unroll
    for (int kt = 0; kt < 2; ++kt) {
      bf16x8 af[4], bfr[4];
#pragma unroll
      for (int i = 0; i < 4; ++i)
        af[i] = *(const bf16x8*)(a_lds + (mw + i * 16 + l16) * 64 + kt * 32 + quad * 8);
#pragma unroll
      for (int i = 0; i < 4; ++i)
        bfr[i] = *(const bf16x8*)(b_lds + (nw + i * 16 + l16) * 64 + kt * 32 + quad * 8);
#pragma unroll
      for (int i = 0; i < 4; ++i)
#pragma unroll
        for (int j = 0; j < 4; ++j)
          acc[i][j] = mfma16(af[i], bfr[j], acc[i][j]);
    }
  }
#pragma unroll
  for (int i = 0; i < 4; ++i) {
#pragma unroll
    for (int j = 0; j < 4; ++j) {
#pragma unroll
      for (int r = 0; r < 4; ++r) {
        const int mrow = m0 + mw + i * 16 + quad * 4 + r;
        const int ncol = n0 + nw + j * 16 + l16;
        S[((size_t)b * SEQ + mrow) * SEQ + ncol] = f2bf(acc[i][j][r] * 0.03125f);
      }
    }
  }
}

// ---------------- row softmax: S bf16 -> P bf16 (normalized, zero-padded) --------
// Writes only cols < (t & ~255)+256  (>= every pvgemm read extent).
__global__ __launch_bounds__(256) void softmax_rows(const short* __restrict__ S,
                                                    short* __restrict__ P) {
  const int row = blockIdx.x;          // 0..8191
  const int t = row & (SEQ - 1);
  const int tid = threadIdx.x;
  const short* __restrict__ srow = S + (size_t)row * SEQ;
  short* __restrict__ prow = P + (size_t)row * SEQ;

  __shared__ float red[4];

  float v[8];
#pragma unroll
  for (int i = 0; i < 8; ++i) {
    const int c = tid + i * 256;
    v[i] = (c <= t) ? bf2f(srow[c]) : -1e30f;
  }
  float m = v[0];
#pragma unroll
  for (int i = 1; i < 8; ++i) m = fmaxf(m, v[i]);
#pragma unroll
  for (int o = 32; o; o >>= 1) m = fmaxf(m, __shfl_xor(m, o));
  if ((tid & 63) == 0) red[tid >> 6] = m;
  __syncthreads();
  m = fmaxf(fmaxf(red[0], red[1]), fmaxf(red[2], red[3]));

  float e[8];
  float s = 0.f;
#pragma unroll
  for (int i = 0; i < 8; ++i) {
    e[i] = __expf(v[i] - m);   // -1e30 - m underflows to 0
    s += e[i];
  }
#pragma unroll
  for (int o = 32; o; o >>= 1) s += __shfl_xor(s, o);
  __syncthreads();
  if ((tid & 63) == 0) red[tid >> 6] = s;
  __syncthreads();
  s = red[0] + red[1] + red[2] + red[3];
  const float rinv = 1.0f / s;
  const int nwr = (t >> 8) + 1;   // chunks to write: covers pvgemm read extent
#pragma unroll
  for (int i = 0; i < 8; ++i)
    if (i < nwr) prow[tid + i * 256] = f2bf(e[i] * rinv);
}

// ---------------- O = P V  (B = V^T layout), causal-truncated K loop -------------
// grid (8,4,16): x=d tile, y=batch, z: m0=(15-z)*128 -> longest-K tiles dispatch
// first (LPT-style balance). out f32 [b][t][d].
__global__ __launch_bounds__(256) void pvgemm(const short* __restrict__ P,
                                              const short* __restrict__ vtb,
                                              float* __restrict__ out) {
  const int n0 = blockIdx.x * 128;
  const int b = blockIdx.y;
  const int m0 = (15 - blockIdx.z) * 128;
  const short* __restrict__ pp = P + (size_t)b * SEQ * SEQ;
  const short* __restrict__ vp = vtb + (size_t)b * D_MODEL * SEQ;
  const int kmax = m0 + 128;

  __shared__ short a_lds[128 * 64];
  __shared__ short b_lds[128 * 64];

  const int tid = threadIdx.x;
  const int wid = tid >> 6;
  const int lane = tid & 63;
  const int quad = lane >> 4;
  const int l16 = lane & 15;
  const int mw = (wid >> 1) * 64;
  const int nw = (wid & 1) * 64;

  f32x4 acc[4][4] = {};

  const int r_local = wid * 8 + (lane >> 3);
  const int c_local = (lane & 7) * 8;

  for (int k0 = 0; k0 < kmax; k0 += 64) {
    __syncthreads();
#pragma unroll
    for (int it = 0; it < 4; ++it) {
      const short* srcA = pp + (size_t)(m0 + it * 32 + r_local) * SEQ + k0 + c_local;
      load_lds16(srcA, (char*)a_lds + (it * 256 + wid * 64) * 16);
      const short* srcB = vp + (size_t)(n0 + it * 32 + r_local) * SEQ + k0 + c_local;
      load_lds16(srcB, (char*)b_lds + (it * 256 + wid * 64) * 16);
    }
    __syncthreads();
#pragma unroll
    for (int kt = 0; kt < 2; ++kt) {
      bf16x8 af[4], bfr[4];
#pragma unroll
      for (int i = 0; i < 4; ++i)
        af[i] = *(const bf16x8*)(a_lds + (mw + i * 16 + l16) * 64 + kt * 32 + quad * 8);
#pragma unroll
      for (int i = 0; i < 4; ++i)
        bfr[i] = *(const bf16x8*)(b_lds + (nw + i * 16 + l16) * 64 + kt * 32 + quad * 8);
#pragma unroll
      for (int i = 0; i < 4; ++i)
#pragma unroll
        for (int j = 0; j < 4; ++j)
          acc[i][j] = mfma16(af[i], bfr[j], acc[i][j]);
    }
  }
#pragma unroll
  for (int i = 0; i < 4; ++i) {
#pragma unroll
    for (int j = 0; j < 4; ++j) {
#pragma unroll
      for (int r = 0; r < 4; ++r) {
        const int mrow = m0 + mw + i * 16 + quad * 4 + r;
        const int ncol = n0 + nw + j * 16 + l16;
        out[((size_t)b * SEQ + mrow) * D_MODEL + ncol] = acc[i][j][r];
      }
    }
  }
}

extern "C" void kernel_launch(void* const* d_in, const int* in_sizes, int n_in,
                              void* d_out, int out_size, void* d_ws, size_t ws_size,
                              hipStream_t stream) {
  (void)in_sizes; (void)n_in; (void)out_size; (void)ws_size;
  const float* x  = (const float*)d_in[0];
  const float* Wq = (const float*)d_in[1];
  const float* bq = (const float*)d_in[2];
  const float* Wk = (const float*)d_in[3];
  const float* bk = (const float*)d_in[4];
  const float* Wv = (const float*)d_in[5];
  const float* bv = (const float*)d_in[6];
  float* out = (float*)d_out;

  char* ws = (char*)d_ws;
  short* xb = (short*)(ws);                 // 16 MB   [dead after qkv_gemm]
  short* wt = (short*)(ws + 16777216);      // 6 MB    [dead after qkv_gemm]
  short* qo = (short*)(ws + 23068672);      // 16 MB   [dead after sgemm]
  short* ko = (short*)(ws + 39845888);      // 16 MB   [dead after sgemm]
  short* vo = (short*)(ws + 56623104);      // 16 MB   transposed [b][d][s]
  short* S  = (short*)(ws + 73400320);      // 32 MB bf16 [b][t][s]
  short* P  = (short*)(ws);                 // 32 MB, aliases xb/wt/qo (dead by then)

  convert_x<<<dim3(8192), dim3(256), 0, stream>>>(x, xb);
  transpose_w<<<dim3(32, 32, 3), dim3(256), 0, stream>>>(Wq, Wk, Wv, wt);
  qkv_gemm<<<dim3(32, 8, 3), dim3(512), 0, stream>>>(xb, wt, bq, bk, bv, qo, ko, vo);
  sgemm<<<dim3(16, 16, BATCH), dim3(256), 0, stream>>>(qo, ko, S);
  softmax_rows<<<dim3(BATCH * SEQ), dim3(256), 0, stream>>>(S, P);
  pvgemm<<<dim3(8, BATCH, 16), dim3(256), 0, stream>>>(P, vo, out);
}

// Round 4
// 266.689 us; speedup vs baseline: 3.0018x; 1.0846x over previous
//
#include <hip/hip_runtime.h>
#include <cstdint>
#include <cmath>

#define D_MODEL 1024
#define SEQ 2048
#define BATCH 4

typedef short bf16x8 __attribute__((ext_vector_type(8)));
typedef float f32x4 __attribute__((ext_vector_type(4)));

__device__ __forceinline__ short f2bf(float f) {
  union { float f; unsigned int u; } v; v.f = f;
  unsigned int r = (v.u + 0x7FFFu + ((v.u >> 16) & 1u)) >> 16;
  return (short)r;
}

__device__ __forceinline__ float bf2f(short h) {
  union { unsigned int u; float f; } v;
  v.u = ((unsigned int)(unsigned short)h) << 16;
  return v.f;
}

__device__ __forceinline__ f32x4 mfma16(bf16x8 a, bf16x8 b, f32x4 c) {
  return __builtin_amdgcn_mfma_f32_16x16x32_bf16(a, b, c, 0, 0, 0);
}

__device__ __forceinline__ void load_lds16(const void* g, void* l) {
  __builtin_amdgcn_global_load_lds(
      (const __attribute__((address_space(1))) unsigned int*)g,
      (__attribute__((address_space(3))) unsigned int*)l, 16, 0, 0);
}

// ---------------- prep: x fp32 -> bf16 ----------------
__global__ __launch_bounds__(256) void convert_x(const float* __restrict__ x,
                                                 short* __restrict__ xb) {
  int i = blockIdx.x * 256 + threadIdx.x;
  float4 f = ((const float4*)x)[i];
  short4 h;
  h.x = f2bf(f.x); h.y = f2bf(f.y); h.z = f2bf(f.z); h.w = f2bf(f.w);
  ((short4*)xb)[i] = h;
}

// ---------------- prep: W [k][n] fp32 -> Wt [n][k] bf16 ----------------
__global__ __launch_bounds__(256) void transpose_w(const float* __restrict__ Wq,
                                                   const float* __restrict__ Wk,
                                                   const float* __restrict__ Wv,
                                                   short* __restrict__ wt) {
  const int mat = blockIdx.z;
  const float* __restrict__ W = (mat == 0) ? Wq : (mat == 1) ? Wk : Wv;
  short* __restrict__ o = wt + (size_t)mat * (D_MODEL * D_MODEL);
  __shared__ float tile[32][33];
  const int k0 = blockIdx.x * 32, n0 = blockIdx.y * 32;
  const int lx = threadIdx.x & 31, ly = threadIdx.x >> 5;
#pragma unroll
  for (int i = 0; i < 4; ++i) {
    int r = ly + i * 8;
    tile[r][lx] = W[(size_t)(k0 + r) * D_MODEL + n0 + lx];
  }
  __syncthreads();
#pragma unroll
  for (int i = 0; i < 4; ++i) {
    int r = ly + i * 8;
    o[(size_t)(n0 + r) * D_MODEL + k0 + lx] = f2bf(tile[lx][r]);
  }
}

// ---------------- QKV GEMM: 256x128 tile, 512 thr, LDS dbuf, XOR swizzle --------
// C[m][n] = sum_k xb[m][k] * Wt[n][k] + bias[n]
__global__ __launch_bounds__(512) void qkv_gemm(
    const short* __restrict__ xb, const short* __restrict__ wt,
    const float* __restrict__ bq, const float* __restrict__ bk,
    const float* __restrict__ bv, short* __restrict__ qo,
    short* __restrict__ ko, short* __restrict__ vo) {
  const int m0 = blockIdx.x * 256;
  const int n0 = blockIdx.y * 128;
  const int mat = blockIdx.z;
  const short* __restrict__ w = wt + (size_t)mat * (D_MODEL * D_MODEL);
  const float* __restrict__ bias = (mat == 0) ? bq : (mat == 1) ? bk : bv;

  __shared__ short a_lds[2][256 * 64];  // 2 x 32 KB
  __shared__ short b_lds[2][128 * 64];  // 2 x 16 KB

  const int tid = threadIdx.x;
  const int wid = tid >> 6;        // 0..7
  const int lane = tid & 63;
  const int quad = lane >> 4;
  const int l16 = lane & 15;
  const int wm = (wid >> 1) * 64;
  const int wn = (wid & 1) * 64;
  const int sw = l16 & 7;                              // read-side swizzle
  const int r_local = wid * 8 + (lane >> 3);           // 0..63
  const int c_sw = ((lane & 7) ^ (lane >> 3)) * 8;     // write-side swizzle

  f32x4 acc[4][4] = {};

  auto stage = [&](int k0, int buf) {
#pragma unroll
    for (int it = 0; it < 4; ++it)
      load_lds16(xb + (size_t)(m0 + it * 64 + r_local) * D_MODEL + k0 + c_sw,
                 (char*)a_lds[buf] + it * 8192 + wid * 1024);
#pragma unroll
    for (int it = 0; it < 2; ++it)
      load_lds16(w + (size_t)(n0 + it * 64 + r_local) * D_MODEL + k0 + c_sw,
                 (char*)b_lds[buf] + it * 8192 + wid * 1024);
  };

  stage(0, 0);
  for (int k0 = 0; k0 < D_MODEL; k0 += 64) {
    const int buf = (k0 >> 6) & 1;
    __syncthreads();
    if (k0 + 64 < D_MODEL) stage(k0 + 64, buf ^ 1);
    const short* al = a_lds[buf];
    const short* bl = b_lds[buf];
#pragma unroll
    for (int kt = 0; kt < 2; ++kt) {
      bf16x8 af[4], bfr[4];
#pragma unroll
      for (int i = 0; i < 4; ++i)
        af[i] = *(const bf16x8*)(al + (wm + i * 16 + l16) * 64 +
                                 ((kt * 4 + quad) ^ sw) * 8);
#pragma unroll
      for (int i = 0; i < 4; ++i)
        bfr[i] = *(const bf16x8*)(bl + (wn + i * 16 + l16) * 64 +
                                  ((kt * 4 + quad) ^ sw) * 8);
#pragma unroll
      for (int i = 0; i < 4; ++i)
#pragma unroll
        for (int j = 0; j < 4; ++j)
          acc[i][j] = mfma16(af[i], bfr[j], acc[i][j]);
    }
  }
#pragma unroll
  for (int i = 0; i < 4; ++i) {
#pragma unroll
    for (int j = 0; j < 4; ++j) {
#pragma unroll
      for (int r = 0; r < 4; ++r) {
        const int mrow = m0 + wm + i * 16 + quad * 4 + r;
        const int ncol = n0 + wn + j * 16 + l16;
        const float val = acc[i][j][r] + bias[ncol];
        const short h = f2bf(val);
        if (mat == 2) {
          const int bb = mrow >> 11;
          const int t = mrow & 2047;
          vo[((size_t)bb * D_MODEL + ncol) * SEQ + t] = h;
        } else if (mat == 0) {
          qo[(size_t)mrow * D_MODEL + ncol] = h;
        } else {
          ko[(size_t)mrow * D_MODEL + ncol] = h;
        }
      }
    }
  }
}

// ---------------- S = scale * Q K^T, causal tiles, dbuf + swizzle ----------------
__global__ __launch_bounds__(256) void sgemm(const short* __restrict__ qb,
                                             const short* __restrict__ kb,
                                             short* __restrict__ S) {
  if (blockIdx.y > blockIdx.x) return;
  const int m0 = blockIdx.x * 128;
  const int n0 = blockIdx.y * 128;
  const int b = blockIdx.z;
  const short* __restrict__ qp = qb + (size_t)b * SEQ * D_MODEL;
  const short* __restrict__ kp = kb + (size_t)b * SEQ * D_MODEL;

  __shared__ short a_lds[2][128 * 64];
  __shared__ short b_lds[2][128 * 64];

  const int tid = threadIdx.x;
  const int wid = tid >> 6;
  const int lane = tid & 63;
  const int quad = lane >> 4;
  const int l16 = lane & 15;
  const int mw = (wid >> 1) * 64;
  const int nw = (wid & 1) * 64;
  const int sw = l16 & 7;
  const int r_local = wid * 8 + (lane >> 3);
  const int c_sw = ((lane & 7) ^ (lane >> 3)) * 8;

  f32x4 acc[4][4] = {};

  auto stage = [&](int k0, int buf) {
#pragma unroll
    for (int it = 0; it < 4; ++it) {
      load_lds16(qp + (size_t)(m0 + it * 32 + r_local) * D_MODEL + k0 + c_sw,
                 (char*)a_lds[buf] + it * 4096 + wid * 1024);
      load_lds16(kp + (size_t)(n0 + it * 32 + r_local) * D_MODEL + k0 + c_sw,
                 (char*)b_lds[buf] + it * 4096 + wid * 1024);
    }
  };

  stage(0, 0);
  for (int k0 = 0; k0 < D_MODEL; k0 += 64) {
    const int buf = (k0 >> 6) & 1;
    __syncthreads();
    if (k0 + 64 < D_MODEL) stage(k0 + 64, buf ^ 1);
    const short* al = a_lds[buf];
    const short* bl = b_lds[buf];
#pragma unroll
    for (int kt = 0; kt < 2; ++kt) {
      bf16x8 af[4], bfr[4];
#pragma unroll
      for (int i = 0; i < 4; ++i)
        af[i] = *(const bf16x8*)(al + (mw + i * 16 + l16) * 64 +
                                 ((kt * 4 + quad) ^ sw) * 8);
#pragma unroll
      for (int i = 0; i < 4; ++i)
        bfr[i] = *(const bf16x8*)(bl + (nw + i * 16 + l16) * 64 +
                                  ((kt * 4 + quad) ^ sw) * 8);
#pragma unroll
      for (int i = 0; i < 4; ++i)
#pragma unroll
        for (int j = 0; j < 4; ++j)
          acc[i][j] = mfma16(af[i], bfr[j], acc[i][j]);
    }
  }
#pragma unroll
  for (int i = 0; i < 4; ++i) {
#pragma unroll
    for (int j = 0; j < 4; ++j) {
#pragma unroll
      for (int r = 0; r < 4; ++r) {
        const int mrow = m0 + mw + i * 16 + quad * 4 + r;
        const int ncol = n0 + nw + j * 16 + l16;
        S[((size_t)b * SEQ + mrow) * SEQ + ncol] = f2bf(acc[i][j][r] * 0.03125f);
      }
    }
  }
}

// ---------------- row softmax: S bf16 -> P bf16 (normalized, zero-padded) --------
__global__ __launch_bounds__(256) void softmax_rows(const short* __restrict__ S,
                                                    short* __restrict__ P) {
  const int row = blockIdx.x;          // 0..8191
  const int t = row & (SEQ - 1);
  const int tid = threadIdx.x;
  const short* __restrict__ srow = S + (size_t)row * SEQ;
  short* __restrict__ prow = P + (size_t)row * SEQ;

  __shared__ float red[4];

  float v[8];
#pragma unroll
  for (int i = 0; i < 8; ++i) {
    const int c = tid + i * 256;
    v[i] = (c <= t) ? bf2f(srow[c]) : -1e30f;
  }
  float m = v[0];
#pragma unroll
  for (int i = 1; i < 8; ++i) m = fmaxf(m, v[i]);
#pragma unroll
  for (int o = 32; o; o >>= 1) m = fmaxf(m, __shfl_xor(m, o));
  if ((tid & 63) == 0) red[tid >> 6] = m;
  __syncthreads();
  m = fmaxf(fmaxf(red[0], red[1]), fmaxf(red[2], red[3]));

  float e[8];
  float s = 0.f;
#pragma unroll
  for (int i = 0; i < 8; ++i) {
    e[i] = __expf(v[i] - m);   // -1e30 - m underflows to 0
    s += e[i];
  }
#pragma unroll
  for (int o = 32; o; o >>= 1) s += __shfl_xor(s, o);
  __syncthreads();
  if ((tid & 63) == 0) red[tid >> 6] = s;
  __syncthreads();
  s = red[0] + red[1] + red[2] + red[3];
  const float rinv = 1.0f / s;
  const int nwr = (t >> 8) + 1;   // chunks to write: covers pvgemm read extent
#pragma unroll
  for (int i = 0; i < 8; ++i)
    if (i < nwr) prow[tid + i * 256] = f2bf(e[i] * rinv);
}

// ---------------- O = P V (B = V^T layout), causal K, dbuf + swizzle -------------
// grid (8,4,16): x=d tile, y=batch, z: m0=(15-z)*128 (LPT: longest-K first).
__global__ __launch_bounds__(256) void pvgemm(const short* __restrict__ P,
                                              const short* __restrict__ vtb,
                                              float* __restrict__ out) {
  const int n0 = blockIdx.x * 128;
  const int b = blockIdx.y;
  const int m0 = (15 - blockIdx.z) * 128;
  const short* __restrict__ pp = P + (size_t)b * SEQ * SEQ;
  const short* __restrict__ vp = vtb + (size_t)b * D_MODEL * SEQ;
  const int kmax = m0 + 128;

  __shared__ short a_lds[2][128 * 64];
  __shared__ short b_lds[2][128 * 64];

  const int tid = threadIdx.x;
  const int wid = tid >> 6;
  const int lane = tid & 63;
  const int quad = lane >> 4;
  const int l16 = lane & 15;
  const int mw = (wid >> 1) * 64;
  const int nw = (wid & 1) * 64;
  const int sw = l16 & 7;
  const int r_local = wid * 8 + (lane >> 3);
  const int c_sw = ((lane & 7) ^ (lane >> 3)) * 8;

  f32x4 acc[4][4] = {};

  auto stage = [&](int k0, int buf) {
#pragma unroll
    for (int it = 0; it < 4; ++it) {
      load_lds16(pp + (size_t)(m0 + it * 32 + r_local) * SEQ + k0 + c_sw,
                 (char*)a_lds[buf] + it * 4096 + wid * 1024);
      load_lds16(vp + (size_t)(n0 + it * 32 + r_local) * SEQ + k0 + c_sw,
                 (char*)b_lds[buf] + it * 4096 + wid * 1024);
    }
  };

  stage(0, 0);
  for (int k0 = 0; k0 < kmax; k0 += 64) {
    const int buf = (k0 >> 6) & 1;
    __syncthreads();
    if (k0 + 64 < kmax) stage(k0 + 64, buf ^ 1);
    const short* al = a_lds[buf];
    const short* bl = b_lds[buf];
#pragma unroll
    for (int kt = 0; kt < 2; ++kt) {
      bf16x8 af[4], bfr[4];
#pragma unroll
      for (int i = 0; i < 4; ++i)
        af[i] = *(const bf16x8*)(al + (mw + i * 16 + l16) * 64 +
                                 ((kt * 4 + quad) ^ sw) * 8);
#pragma unroll
      for (int i = 0; i < 4; ++i)
        bfr[i] = *(const bf16x8*)(bl + (nw + i * 16 + l16) * 64 +
                                  ((kt * 4 + quad) ^ sw) * 8);
#pragma unroll
      for (int i = 0; i < 4; ++i)
#pragma unroll
        for (int j = 0; j < 4; ++j)
          acc[i][j] = mfma16(af[i], bfr[j], acc[i][j]);
    }
  }
#pragma unroll
  for (int i = 0; i < 4; ++i) {
#pragma unroll
    for (int j = 0; j < 4; ++j) {
#pragma unroll
      for (int r = 0; r < 4; ++r) {
        const int mrow = m0 + mw + i * 16 + quad * 4 + r;
        const int ncol = n0 + nw + j * 16 + l16;
        out[((size_t)b * SEQ + mrow) * D_MODEL + ncol] = acc[i][j][r];
      }
    }
  }
}

extern "C" void kernel_launch(void* const* d_in, const int* in_sizes, int n_in,
                              void* d_out, int out_size, void* d_ws, size_t ws_size,
                              hipStream_t stream) {
  (void)in_sizes; (void)n_in; (void)out_size; (void)ws_size;
  const float* x  = (const float*)d_in[0];
  const float* Wq = (const float*)d_in[1];
  const float* bq = (const float*)d_in[2];
  const float* Wk = (const float*)d_in[3];
  const float* bk = (const float*)d_in[4];
  const float* Wv = (const float*)d_in[5];
  const float* bv = (const float*)d_in[6];
  float* out = (float*)d_out;

  char* ws = (char*)d_ws;
  short* xb = (short*)(ws);                 // 16 MB   [dead after qkv_gemm]
  short* wt = (short*)(ws + 16777216);      // 6 MB    [dead after qkv_gemm]
  short* qo = (short*)(ws + 23068672);      // 16 MB   [dead after sgemm]
  short* ko = (short*)(ws + 39845888);      // 16 MB   [dead after sgemm]
  short* vo = (short*)(ws + 56623104);      // 16 MB   transposed [b][d][s]
  short* S  = (short*)(ws + 73400320);      // 32 MB bf16 [b][t][s]
  short* P  = (short*)(ws);                 // 32 MB, aliases xb/wt/qo (dead by then)

  convert_x<<<dim3(8192), dim3(256), 0, stream>>>(x, xb);
  transpose_w<<<dim3(32, 32, 3), dim3(256), 0, stream>>>(Wq, Wk, Wv, wt);
  qkv_gemm<<<dim3(32, 8, 3), dim3(512), 0, stream>>>(xb, wt, bq, bk, bv, qo, ko, vo);
  sgemm<<<dim3(16, 16, BATCH), dim3(256), 0, stream>>>(qo, ko, S);
  softmax_rows<<<dim3(BATCH * SEQ), dim3(256), 0, stream>>>(S, P);
  pvgemm<<<dim3(8, BATCH, 16), dim3(256), 0, stream>>>(P, vo, out);
}

// Round 5
// 263.332 us; speedup vs baseline: 3.0400x; 1.0127x over previous
//
#include <hip/hip_runtime.h>
#include <cstdint>
#include <cmath>

#define D_MODEL 1024
#define SEQ 2048
#define BATCH 4

typedef short bf16x8 __attribute__((ext_vector_type(8)));
typedef float f32x4 __attribute__((ext_vector_type(4)));

__device__ __forceinline__ short f2bf(float f) {
  union { float f; unsigned int u; } v; v.f = f;
  unsigned int r = (v.u + 0x7FFFu + ((v.u >> 16) & 1u)) >> 16;
  return (short)r;
}

__device__ __forceinline__ float bf2f(short h) {
  union { unsigned int u; float f; } v;
  v.u = ((unsigned int)(unsigned short)h) << 16;
  return v.f;
}

__device__ __forceinline__ f32x4 mfma16(bf16x8 a, bf16x8 b, f32x4 c) {
  return __builtin_amdgcn_mfma_f32_16x16x32_bf16(a, b, c, 0, 0, 0);
}

__device__ __forceinline__ void load_lds16(const void* g, void* l) {
  __builtin_amdgcn_global_load_lds(
      (const __attribute__((address_space(1))) unsigned int*)g,
      (__attribute__((address_space(3))) unsigned int*)l, 16, 0, 0);
}

// ---------------- prep: x fp32 -> bf16 ----------------
__global__ __launch_bounds__(256) void convert_x(const float* __restrict__ x,
                                                 short* __restrict__ xb) {
  int i = blockIdx.x * 256 + threadIdx.x;
  float4 f = ((const float4*)x)[i];
  short4 h;
  h.x = f2bf(f.x); h.y = f2bf(f.y); h.z = f2bf(f.z); h.w = f2bf(f.w);
  ((short4*)xb)[i] = h;
}

// ---------------- prep: W [k][n] fp32 -> Wt [n][k] bf16 ----------------
__global__ __launch_bounds__(256) void transpose_w(const float* __restrict__ Wq,
                                                   const float* __restrict__ Wk,
                                                   const float* __restrict__ Wv,
                                                   short* __restrict__ wt) {
  const int mat = blockIdx.z;
  const float* __restrict__ W = (mat == 0) ? Wq : (mat == 1) ? Wk : Wv;
  short* __restrict__ o = wt + (size_t)mat * (D_MODEL * D_MODEL);
  __shared__ float tile[32][33];
  const int k0 = blockIdx.x * 32, n0 = blockIdx.y * 32;
  const int lx = threadIdx.x & 31, ly = threadIdx.x >> 5;
#pragma unroll
  for (int i = 0; i < 4; ++i) {
    int r = ly + i * 8;
    tile[r][lx] = W[(size_t)(k0 + r) * D_MODEL + n0 + lx];
  }
  __syncthreads();
#pragma unroll
  for (int i = 0; i < 4; ++i) {
    int r = ly + i * 8;
    o[(size_t)(n0 + r) * D_MODEL + k0 + lx] = f2bf(tile[lx][r]);
  }
}

// ------- QKV GEMM: 256x128 tile, 512 thr, BK=32, dbuf (48 KB -> 2 WGs/CU) -------
// C[m][n] = sum_k xb[m][k] * Wt[n][k] + bias[n]
// LDS chunk pos p of row r holds global 8-elem chunk p ^ ((r>>1)&3).
__global__ __launch_bounds__(512, 4) void qkv_gemm(
    const short* __restrict__ xb, const short* __restrict__ wt,
    const float* __restrict__ bq, const float* __restrict__ bk,
    const float* __restrict__ bv, short* __restrict__ qo,
    short* __restrict__ ko, short* __restrict__ vo) {
  const int m0 = blockIdx.x * 256;
  const int n0 = blockIdx.y * 128;
  const int mat = blockIdx.z;
  const short* __restrict__ w = wt + (size_t)mat * (D_MODEL * D_MODEL);
  const float* __restrict__ bias = (mat == 0) ? bq : (mat == 1) ? bk : bv;

  __shared__ short a_lds[2][256 * 32];  // 2 x 16 KB
  __shared__ short b_lds[2][128 * 32];  // 2 x 8 KB

  const int tid = threadIdx.x;
  const int wid = tid >> 6;        // 0..7
  const int lane = tid & 63;
  const int quad = lane >> 4;
  const int l16 = lane & 15;
  const int wm = (wid >> 1) * 64;
  const int wn = (wid & 1) * 64;
  const int key = (l16 >> 1) & 3;  // read-side swizzle key (2-way max conflict)

  f32x4 acc[4][4] = {};

  auto stage = [&](int k0, int buf) {
    // A: 1024 16B-chunks, 2 per thread; chunk c -> row c>>2, lds pos c&3,
    // global chunk (c&3)^((c>>3)&3)
#pragma unroll
    for (int h = 0; h < 2; ++h) {
      const int c = tid + h * 512;
      load_lds16(xb + (size_t)(m0 + (c >> 2)) * D_MODEL + k0 +
                     (((c & 3) ^ ((c >> 3) & 3)) << 3),
                 (char*)&a_lds[buf][c * 8]);
    }
    // B: 512 chunks, 1 per thread
    load_lds16(w + (size_t)(n0 + (tid >> 2)) * D_MODEL + k0 +
                   (((tid & 3) ^ ((tid >> 3) & 3)) << 3),
               (char*)&b_lds[buf][tid * 8]);
  };

  stage(0, 0);
  for (int k0 = 0; k0 < D_MODEL; k0 += 32) {
    const int buf = (k0 >> 5) & 1;
    __syncthreads();
    if (k0 + 32 < D_MODEL) stage(k0 + 32, buf ^ 1);
    const short* al = a_lds[buf];
    const short* bl = b_lds[buf];
    bf16x8 af[4], bfr[4];
#pragma unroll
    for (int i = 0; i < 4; ++i)
      af[i] = *(const bf16x8*)(al + (wm + i * 16 + l16) * 32 +
                               ((quad ^ key) << 3));
#pragma unroll
    for (int j = 0; j < 4; ++j)
      bfr[j] = *(const bf16x8*)(bl + (wn + j * 16 + l16) * 32 +
                                ((quad ^ key) << 3));
#pragma unroll
    for (int i = 0; i < 4; ++i)
#pragma unroll
      for (int j = 0; j < 4; ++j)
        acc[i][j] = mfma16(af[i], bfr[j], acc[i][j]);
  }
#pragma unroll
  for (int i = 0; i < 4; ++i) {
#pragma unroll
    for (int j = 0; j < 4; ++j) {
#pragma unroll
      for (int r = 0; r < 4; ++r) {
        const int mrow = m0 + wm + i * 16 + quad * 4 + r;
        const int ncol = n0 + wn + j * 16 + l16;
        const float val = acc[i][j][r] + bias[ncol];
        const short h = f2bf(val);
        if (mat == 2) {
          const int bb = mrow >> 11;
          const int t = mrow & 2047;
          vo[((size_t)bb * D_MODEL + ncol) * SEQ + t] = h;
        } else if (mat == 0) {
          qo[(size_t)mrow * D_MODEL + ncol] = h;
        } else {
          ko[(size_t)mrow * D_MODEL + ncol] = h;
        }
      }
    }
  }
}

// ---------------- S = scale * Q K^T, causal tiles, dbuf + swizzle ----------------
__global__ __launch_bounds__(256) void sgemm(const short* __restrict__ qb,
                                             const short* __restrict__ kb,
                                             short* __restrict__ S) {
  if (blockIdx.y > blockIdx.x) return;
  const int m0 = blockIdx.x * 128;
  const int n0 = blockIdx.y * 128;
  const int b = blockIdx.z;
  const short* __restrict__ qp = qb + (size_t)b * SEQ * D_MODEL;
  const short* __restrict__ kp = kb + (size_t)b * SEQ * D_MODEL;

  __shared__ short a_lds[2][128 * 64];
  __shared__ short b_lds[2][128 * 64];

  const int tid = threadIdx.x;
  const int wid = tid >> 6;
  const int lane = tid & 63;
  const int quad = lane >> 4;
  const int l16 = lane & 15;
  const int mw = (wid >> 1) * 64;
  const int nw = (wid & 1) * 64;
  const int sw = l16 & 7;
  const int r_local = wid * 8 + (lane >> 3);
  const int c_sw = ((lane & 7) ^ (lane >> 3)) * 8;

  f32x4 acc[4][4] = {};

  auto stage = [&](int k0, int buf) {
#pragma unroll
    for (int it = 0; it < 4; ++it) {
      load_lds16(qp + (size_t)(m0 + it * 32 + r_local) * D_MODEL + k0 + c_sw,
                 (char*)a_lds[buf] + it * 4096 + wid * 1024);
      load_lds16(kp + (size_t)(n0 + it * 32 + r_local) * D_MODEL + k0 + c_sw,
                 (char*)b_lds[buf] + it * 4096 + wid * 1024);
    }
  };

  stage(0, 0);
  for (int k0 = 0; k0 < D_MODEL; k0 += 64) {
    const int buf = (k0 >> 6) & 1;
    __syncthreads();
    if (k0 + 64 < D_MODEL) stage(k0 + 64, buf ^ 1);
    const short* al = a_lds[buf];
    const short* bl = b_lds[buf];
#pragma unroll
    for (int kt = 0; kt < 2; ++kt) {
      bf16x8 af[4], bfr[4];
#pragma unroll
      for (int i = 0; i < 4; ++i)
        af[i] = *(const bf16x8*)(al + (mw + i * 16 + l16) * 64 +
                                 ((kt * 4 + quad) ^ sw) * 8);
#pragma unroll
      for (int i = 0; i < 4; ++i)
        bfr[i] = *(const bf16x8*)(bl + (nw + i * 16 + l16) * 64 +
                                  ((kt * 4 + quad) ^ sw) * 8);
#pragma unroll
      for (int i = 0; i < 4; ++i)
#pragma unroll
        for (int j = 0; j < 4; ++j)
          acc[i][j] = mfma16(af[i], bfr[j], acc[i][j]);
    }
  }
#pragma unroll
  for (int i = 0; i < 4; ++i) {
#pragma unroll
    for (int j = 0; j < 4; ++j) {
#pragma unroll
      for (int r = 0; r < 4; ++r) {
        const int mrow = m0 + mw + i * 16 + quad * 4 + r;
        const int ncol = n0 + nw + j * 16 + l16;
        S[((size_t)b * SEQ + mrow) * SEQ + ncol] = f2bf(acc[i][j][r] * 0.03125f);
      }
    }
  }
}

// ---------------- row softmax: S bf16 -> P bf16 (normalized, zero-padded) --------
__global__ __launch_bounds__(256) void softmax_rows(const short* __restrict__ S,
                                                    short* __restrict__ P) {
  const int row = blockIdx.x;          // 0..8191
  const int t = row & (SEQ - 1);
  const int tid = threadIdx.x;
  const short* __restrict__ srow = S + (size_t)row * SEQ;
  short* __restrict__ prow = P + (size_t)row * SEQ;

  __shared__ float red[4];

  float v[8];
#pragma unroll
  for (int i = 0; i < 8; ++i) {
    const int c = tid + i * 256;
    v[i] = (c <= t) ? bf2f(srow[c]) : -1e30f;
  }
  float m = v[0];
#pragma unroll
  for (int i = 1; i < 8; ++i) m = fmaxf(m, v[i]);
#pragma unroll
  for (int o = 32; o; o >>= 1) m = fmaxf(m, __shfl_xor(m, o));
  if ((tid & 63) == 0) red[tid >> 6] = m;
  __syncthreads();
  m = fmaxf(fmaxf(red[0], red[1]), fmaxf(red[2], red[3]));

  float e[8];
  float s = 0.f;
#pragma unroll
  for (int i = 0; i < 8; ++i) {
    e[i] = __expf(v[i] - m);   // -1e30 - m underflows to 0
    s += e[i];
  }
#pragma unroll
  for (int o = 32; o; o >>= 1) s += __shfl_xor(s, o);
  __syncthreads();
  if ((tid & 63) == 0) red[tid >> 6] = s;
  __syncthreads();
  s = red[0] + red[1] + red[2] + red[3];
  const float rinv = 1.0f / s;
  const int nwr = (t >> 8) + 1;   // chunks to write: covers pvgemm read extent
#pragma unroll
  for (int i = 0; i < 8; ++i)
    if (i < nwr) prow[tid + i * 256] = f2bf(e[i] * rinv);
}

// ---------------- O = P V (B = V^T layout), causal K, dbuf + swizzle -------------
// grid (8,4,16): x=d tile, y=batch, z: m0=(15-z)*128 (LPT: longest-K first).
__global__ __launch_bounds__(256) void pvgemm(const short* __restrict__ P,
                                              const short* __restrict__ vtb,
                                              float* __restrict__ out) {
  const int n0 = blockIdx.x * 128;
  const int b = blockIdx.y;
  const int m0 = (15 - blockIdx.z) * 128;
  const short* __restrict__ pp = P + (size_t)b * SEQ * SEQ;
  const short* __restrict__ vp = vtb + (size_t)b * D_MODEL * SEQ;
  const int kmax = m0 + 128;

  __shared__ short a_lds[2][128 * 64];
  __shared__ short b_lds[2][128 * 64];

  const int tid = threadIdx.x;
  const int wid = tid >> 6;
  const int lane = tid & 63;
  const int quad = lane >> 4;
  const int l16 = lane & 15;
  const int mw = (wid >> 1) * 64;
  const int nw = (wid & 1) * 64;
  const int sw = l16 & 7;
  const int r_local = wid * 8 + (lane >> 3);
  const int c_sw = ((lane & 7) ^ (lane >> 3)) * 8;

  f32x4 acc[4][4] = {};

  auto stage = [&](int k0, int buf) {
#pragma unroll
    for (int it = 0; it < 4; ++it) {
      load_lds16(pp + (size_t)(m0 + it * 32 + r_local) * SEQ + k0 + c_sw,
                 (char*)a_lds[buf] + it * 4096 + wid * 1024);
      load_lds16(vp + (size_t)(n0 + it * 32 + r_local) * SEQ + k0 + c_sw,
                 (char*)b_lds[buf] + it * 4096 + wid * 1024);
    }
  };

  stage(0, 0);
  for (int k0 = 0; k0 < kmax; k0 += 64) {
    const int buf = (k0 >> 6) & 1;
    __syncthreads();
    if (k0 + 64 < kmax) stage(k0 + 64, buf ^ 1);
    const short* al = a_lds[buf];
    const short* bl = b_lds[buf];
#pragma unroll
    for (int kt = 0; kt < 2; ++kt) {
      bf16x8 af[4], bfr[4];
#pragma unroll
      for (int i = 0; i < 4; ++i)
        af[i] = *(const bf16x8*)(al + (mw + i * 16 + l16) * 64 +
                                 ((kt * 4 + quad) ^ sw) * 8);
#pragma unroll
      for (int i = 0; i < 4; ++i)
        bfr[i] = *(const bf16x8*)(bl + (nw + i * 16 + l16) * 64 +
                                  ((kt * 4 + quad) ^ sw) * 8);
#pragma unroll
      for (int i = 0; i < 4; ++i)
#pragma unroll
        for (int j = 0; j < 4; ++j)
          acc[i][j] = mfma16(af[i], bfr[j], acc[i][j]);
    }
  }
#pragma unroll
  for (int i = 0; i < 4; ++i) {
#pragma unroll
    for (int j = 0; j < 4; ++j) {
#pragma unroll
      for (int r = 0; r < 4; ++r) {
        const int mrow = m0 + mw + i * 16 + quad * 4 + r;
        const int ncol = n0 + nw + j * 16 + l16;
        out[((size_t)b * SEQ + mrow) * D_MODEL + ncol] = acc[i][j][r];
      }
    }
  }
}

extern "C" void kernel_launch(void* const* d_in, const int* in_sizes, int n_in,
                              void* d_out, int out_size, void* d_ws, size_t ws_size,
                              hipStream_t stream) {
  (void)in_sizes; (void)n_in; (void)out_size; (void)ws_size;
  const float* x  = (const float*)d_in[0];
  const float* Wq = (const float*)d_in[1];
  const float* bq = (const float*)d_in[2];
  const float* Wk = (const float*)d_in[3];
  const float* bk = (const float*)d_in[4];
  const float* Wv = (const float*)d_in[5];
  const float* bv = (const float*)d_in[6];
  float* out = (float*)d_out;

  char* ws = (char*)d_ws;
  short* xb = (short*)(ws);                 // 16 MB   [dead after qkv_gemm]
  short* wt = (short*)(ws + 16777216);      // 6 MB    [dead after qkv_gemm]
  short* qo = (short*)(ws + 23068672);      // 16 MB   [dead after sgemm]
  short* ko = (short*)(ws + 39845888);      // 16 MB   [dead after sgemm]
  short* vo = (short*)(ws + 56623104);      // 16 MB   transposed [b][d][s]
  short* S  = (short*)(ws + 73400320);      // 32 MB bf16 [b][t][s]
  short* P  = (short*)(ws);                 // 32 MB, aliases xb/wt/qo (dead by then)

  convert_x<<<dim3(8192), dim3(256), 0, stream>>>(x, xb);
  transpose_w<<<dim3(32, 32, 3), dim3(256), 0, stream>>>(Wq, Wk, Wv, wt);
  qkv_gemm<<<dim3(32, 8, 3), dim3(512), 0, stream>>>(xb, wt, bq, bk, bv, qo, ko, vo);
  sgemm<<<dim3(16, 16, BATCH), dim3(256), 0, stream>>>(qo, ko, S);
  softmax_rows<<<dim3(BATCH * SEQ), dim3(256), 0, stream>>>(S, P);
  pvgemm<<<dim3(8, BATCH, 16), dim3(256), 0, stream>>>(P, vo, out);
}